// Round 2
// baseline (91.886 us; speedup 1.0000x reference)
//
#include <hip/hip_runtime.h>
#include <hip/hip_bf16.h>
#include <stdint.h>

#define NB  256     // batch
#define NSP 128     // n_spins
#define DM  768     // d_model
#define KMC 25      // coalitions
#define MROWS (NB*KMC)  // 6400

// workspace layout (bytes), all 256-aligned
#define OFF_S    0u          // s bf16 [6400][768]          9,830,400 B
#define OFF_WT   9830400u    // w_v^T bf16 [768][768]       1,179,648 B
#define OFF_N2   11010048u   // norm2 f32 [6400]               25,600 B
#define OFF_COEF 11035648u   // coefT f32 [128][28]            14,336 B
#define OFF_CFS  11049984u   // cfS  f32 [128][32] (0/1 pad)   16,384 B

typedef __attribute__((ext_vector_type(8))) short bf16x8;
typedef __attribute__((ext_vector_type(4))) float f32x4;
typedef unsigned int u32;

#define GLOAD_LDS16(gp, lp) \
  __builtin_amdgcn_global_load_lds((const __attribute__((address_space(1))) u32*)(gp), \
                                   (__attribute__((address_space(3))) u32*)(lp), 16, 0, 0)

// ---------------- prep: transpose w_v -> bf16 wT, coef tables, zero norm2 ---
__global__ __launch_bounds__(256) void prep_kernel(const float* __restrict__ wv,
                                                   const int* __restrict__ co,
                                                   char* __restrict__ ws) {
  const int blk = blockIdx.x;
  const int t = threadIdx.x;
  if (blk < 144) {               // 12x12 tiles of 64x64: wT[n][k] = bf16(wv[k][n])
    __shared__ __hip_bfloat16 lt[64][66];
    const int bi = blk / 12, bj = blk % 12;
    const int k0 = bi * 64, n0 = bj * 64;
    #pragma unroll
    for (int i = 0; i < 16; ++i) {
      int idx = t + i * 256;
      int r = idx >> 6, c = idx & 63;
      lt[c][r] = __float2bfloat16(wv[(size_t)(k0 + r) * DM + n0 + c]);
    }
    __syncthreads();
    __hip_bfloat16* wT = (__hip_bfloat16*)(ws + OFF_WT);
    #pragma unroll
    for (int i = 0; i < 16; ++i) {
      int idx = t + i * 256;
      int r = idx >> 6, c = idx & 63;
      wT[(size_t)(n0 + r) * DM + k0 + c] = lt[r][c];
    }
  } else if (blk == 144) {       // per-(n,k) shapley coefficients + c-float table
    if (t < NSP) {
      const int n = t;
      int cw = 0;
      for (int k = 0; k < KMC; ++k) cw += co[k * NSP + n];
      const int cwo = KMC - cw;
      const bool valid = (cw > 0) && (cwo > 0);
      float* coefT = (float*)(ws + OFF_COEF);
      float* cfS = (float*)(ws + OFF_CFS);
      for (int k = 0; k < 28; ++k) {
        float v = 0.f;
        if (valid && k < KMC) v = co[k * NSP + n] ? (1.f / (float)cw) : (-1.f / (float)cwo);
        coefT[n * 28 + k] = v;
      }
      for (int k = 0; k < 32; ++k)
        cfS[n * 32 + k] = (k < KMC) ? (float)co[k * NSP + n] : 0.f;
    }
  } else {                       // zero norm2 accumulators
    int i = (blk - 145) * 256 + t;
    if (i < MROWS) ((float*)(ws + OFF_N2))[i] = 0.f;
  }
}

// ---------------- kernel A: s[b,k,:] = sum_n c[k,n] * f[b,n,:], write bf16 ---
// Coalition row is wave-uniform -> scalar (s_load) path, zero LDS in the loop.
__global__ __launch_bounds__(192) void kA(const float* __restrict__ f,
                                          char* __restrict__ ws) {
  const int b = blockIdx.x;
  const int half = blockIdx.y;     // d-half (0: d<384, 1: d>=384)
  const int t = threadIdx.x;
  const float* __restrict__ cfS = (const float*)(ws + OFF_CFS);
  const int d0 = half * 384 + t * 2;
  const float* fb = f + (size_t)b * NSP * DM + d0;

  float2 acc[KMC];
  #pragma unroll
  for (int k = 0; k < KMC; ++k) { acc[k].x = 0.f; acc[k].y = 0.f; }

  float2 vbuf[16];                 // 16-deep global prefetch (8 KB/wave in flight)
  #pragma unroll
  for (int p = 0; p < 16; ++p) vbuf[p] = *(const float2*)(fb + (size_t)p * DM);

  #pragma unroll 4
  for (int n = 0; n < NSP; ++n) {
    float2 v = vbuf[n & 15];
    if (n + 16 < NSP) vbuf[n & 15] = *(const float2*)(fb + (size_t)(n + 16) * DM);
    const float* __restrict__ cfn = cfS + n * 32;   // uniform addr -> s_load
    #pragma unroll
    for (int k = 0; k < KMC; ++k) {
      float c = cfn[k];            // SGPR; v_fmac_f32 dst, s, v
      acc[k].x = fmaf(c, v.x, acc[k].x);
      acc[k].y = fmaf(c, v.y, acc[k].y);
    }
  }

  __hip_bfloat16* s = (__hip_bfloat16*)(ws + OFF_S);
  #pragma unroll
  for (int k = 0; k < KMC; ++k) {
    union { unsigned short h[2]; u32 u; } pk;
    __hip_bfloat16 h0 = __float2bfloat16(acc[k].x);
    __hip_bfloat16 h1 = __float2bfloat16(acc[k].y);
    pk.h[0] = *(unsigned short*)&h0;
    pk.h[1] = *(unsigned short*)&h1;
    *(u32*)((char*)(s + (size_t)(b * KMC + k) * DM + d0)) = pk.u;
  }
}

// ---------------- kernel B: norm2[row] += rowwise |s @ wT^T|^2 (bf16 MFMA) ---
#define BM 128
#define BN 192
#define BK 32
#define NTK 24   // 768/32

__global__ __launch_bounds__(256) void kB(char* __restrict__ ws) {
  const int bid = blockIdx.x;      // grid 200 = 50 (M) * 4 (N)
  const int tm = bid >> 2;
  const int tn = bid & 3;
  const int tid = threadIdx.x;
  const int wid = tid >> 6;
  const int lane = tid & 63;
  const int wm = wid >> 1;         // 2x2 wave grid: 64 rows x 96 cols per wave
  const int wn = wid & 1;

  const __hip_bfloat16* S  = (const __hip_bfloat16*)(ws + OFF_S);
  const __hip_bfloat16* WT = (const __hip_bfloat16*)(ws + OFF_WT);
  float* norm2 = (float*)(ws + OFF_N2);

  __shared__ __align__(16) char As[2][BM * BK * 2];  // [128][32] bf16, 64B rows
  __shared__ __align__(16) char Bs[2][BN * BK * 2];  // [192][32] bf16, 64B rows

  // staging: global src pre-swizzled (slot ^= (r>>1)&3), LDS dest linear
  const char* gA[2]; char *lA0[2], *lA1[2];
  #pragma unroll
  for (int j = 0; j < 2; ++j) {
    int li = (wid * 2 + j) * 64 + lane;
    int r = li >> 2, sl = li & 3;
    int slx = sl ^ ((r >> 1) & 3);
    gA[j] = (const char*)(S + (size_t)(tm * BM + r) * DM) + slx * 16;
    lA0[j] = As[0] + (wid * 2 + j) * 1024;
    lA1[j] = As[1] + (wid * 2 + j) * 1024;
  }
  const char* gB[3]; char *lB0[3], *lB1[3];
  #pragma unroll
  for (int j = 0; j < 3; ++j) {
    int li = (wid * 3 + j) * 64 + lane;
    int r = li >> 2, sl = li & 3;
    int slx = sl ^ ((r >> 1) & 3);
    gB[j] = (const char*)(WT + (size_t)(tn * BN + r) * DM) + slx * 16;
    lB0[j] = Bs[0] + (wid * 3 + j) * 1024;
    lB1[j] = Bs[1] + (wid * 3 + j) * 1024;
  }

  auto stage = [&](int tk, int bsel) {
    size_t koff = (size_t)tk * (BK * 2);   // 64 bytes per K-step
    #pragma unroll
    for (int j = 0; j < 2; ++j) GLOAD_LDS16(gA[j] + koff, bsel ? lA1[j] : lA0[j]);
    #pragma unroll
    for (int j = 0; j < 3; ++j) GLOAD_LDS16(gB[j] + koff, bsel ? lB1[j] : lB0[j]);
  };

  f32x4 acc[4][6];
  #pragma unroll
  for (int m = 0; m < 4; ++m)
    #pragma unroll
    for (int n = 0; n < 6; ++n)
      #pragma unroll
      for (int j = 0; j < 4; ++j) acc[m][n][j] = 0.f;

  // fragment read offsets (swizzled to match stage-source permutation)
  int offA[4], offB[6];
  #pragma unroll
  for (int m = 0; m < 4; ++m) {
    int r = wm * 64 + m * 16 + (lane & 15);
    int sl = (lane >> 4) ^ ((r >> 1) & 3);
    offA[m] = r * 64 + sl * 16;
  }
  #pragma unroll
  for (int n = 0; n < 6; ++n) {
    int r = wn * 96 + n * 16 + (lane & 15);
    int sl = (lane >> 4) ^ ((r >> 1) & 3);
    offB[n] = r * 64 + sl * 16;
  }

  stage(0, 0);
  for (int tk = 0; tk < NTK; ++tk) {
    int cur = tk & 1;
    __syncthreads();               // drains vmcnt(0): staged tile ready
    if (tk + 1 < NTK) stage(tk + 1, cur ^ 1);
    bf16x8 af[4], bfr[6];
    #pragma unroll
    for (int m = 0; m < 4; ++m) af[m] = *(const bf16x8*)(As[cur] + offA[m]);
    #pragma unroll
    for (int n = 0; n < 6; ++n) bfr[n] = *(const bf16x8*)(Bs[cur] + offB[n]);
    #pragma unroll
    for (int m = 0; m < 4; ++m)
      #pragma unroll
      for (int n = 0; n < 6; ++n)
        acc[m][n] = __builtin_amdgcn_mfma_f32_16x16x32_bf16(af[m], bfr[n], acc[m][n], 0, 0, 0);
  }

  // epilogue: sum of squares over this block's 96-col slice, reduce 16 lanes,
  // atomicAdd into norm2[row]  (C/D layout: col=lane&15, row=(lane>>4)*4+reg)
  float ps[4][4];
  #pragma unroll
  for (int m = 0; m < 4; ++m)
    #pragma unroll
    for (int i = 0; i < 4; ++i) {
      float v = 0.f;
      #pragma unroll
      for (int n = 0; n < 6; ++n) { float x = acc[m][n][i]; v += x * x; }
      #pragma unroll
      for (int d = 1; d < 16; d <<= 1) v += __shfl_xor(v, d, 64);
      ps[m][i] = v;
    }
  if ((lane & 15) == 0) {
    int g = lane >> 4;
    #pragma unroll
    for (int m = 0; m < 4; ++m)
      #pragma unroll
      for (int i = 0; i < 4; ++i)
        atomicAdd(&norm2[tm * BM + wm * 64 + m * 16 + g * 4 + i], ps[m][i]);
  }
}

// ---------------- kernel C: cv = relu(sqrt(norm2)*scale); shapley ------------
__global__ __launch_bounds__(128) void kC(const char* __restrict__ ws,
                                          const float* __restrict__ scale,
                                          float* __restrict__ out) {
  const int b = blockIdx.x, n = threadIdx.x;
  const float* norm2 = (const float*)(ws + OFF_N2);
  const float* coefT = (const float*)(ws + OFF_COEF);
  __shared__ float cvs[32];
  if (n < KMC) {
    float nv = norm2[b * KMC + n];
    cvs[n] = fmaxf(sqrtf(fmaxf(nv, 0.f)) * scale[0], 0.f);
  } else if (n < 32) {
    cvs[n] = 0.f;
  }
  __syncthreads();
  float sum = 0.f;
  #pragma unroll
  for (int k = 0; k < KMC; ++k) sum += cvs[k] * coefT[n * 28 + k];
  out[b * NSP + n] = sum;
}

extern "C" void kernel_launch(void* const* d_in, const int* in_sizes, int n_in,
                              void* d_out, int out_size, void* d_ws, size_t ws_size,
                              hipStream_t stream) {
  const float* features   = (const float*)d_in[0];
  const int*   coalitions = (const int*)d_in[1];
  const float* wv         = (const float*)d_in[2];
  const float* scale      = (const float*)d_in[3];
  char* ws = (char*)d_ws;

  prep_kernel<<<171, 256, 0, stream>>>(wv, coalitions, ws);
  dim3 ga(NB, 2);
  kA<<<ga, 192, 0, stream>>>(features, ws);
  kB<<<200, 256, 0, stream>>>(ws);
  kC<<<NB, 128, 0, stream>>>(ws, scale, (float*)d_out);
}

// Round 3
// 64.108 us; speedup vs baseline: 1.4333x; 1.4333x over previous
//
#include <hip/hip_runtime.h>
#include <hip/hip_bf16.h>
#include <stdint.h>

#define NB  256     // batch
#define NSP 128     // n_spins
#define DM  768     // d_model
#define KMC 25      // coalitions
#define MROWS (NB*KMC)  // 6400

// workspace layout (bytes), all 256-aligned
#define OFF_S    0u          // s bf16 [6400][768]          9,830,400 B
#define OFF_WT   9830400u    // w_v^T bf16 [768][768]       1,179,648 B
#define OFF_N2   11010048u   // norm2 f32 [6400]               25,600 B
#define OFF_COEF 11035648u   // coefT f32 [128][28]            14,336 B
#define OFF_CFS  11049984u   // cfS  f32 [128][32] (0/1 pad)   16,384 B

typedef __attribute__((ext_vector_type(8))) short bf16x8;
typedef __attribute__((ext_vector_type(4))) float f32x4;
typedef unsigned int u32;

#define GLOAD_LDS16(gp, lp) \
  __builtin_amdgcn_global_load_lds((const __attribute__((address_space(1))) u32*)(gp), \
                                   (__attribute__((address_space(3))) u32*)(lp), 16, 0, 0)

// ---------------- prep: transpose w_v -> bf16 wT, coef tables, zero norm2 ---
__global__ __launch_bounds__(256) void prep_kernel(const float* __restrict__ wv,
                                                   const int* __restrict__ co,
                                                   char* __restrict__ ws) {
  const int blk = blockIdx.x;
  const int t = threadIdx.x;
  if (blk < 144) {               // 12x12 tiles of 64x64: wT[n][k] = bf16(wv[k][n])
    __shared__ __hip_bfloat16 lt[64][66];
    const int bi = blk / 12, bj = blk % 12;
    const int k0 = bi * 64, n0 = bj * 64;
    #pragma unroll
    for (int i = 0; i < 16; ++i) {
      int idx = t + i * 256;
      int r = idx >> 6, c = idx & 63;
      lt[c][r] = __float2bfloat16(wv[(size_t)(k0 + r) * DM + n0 + c]);
    }
    __syncthreads();
    __hip_bfloat16* wT = (__hip_bfloat16*)(ws + OFF_WT);
    #pragma unroll
    for (int i = 0; i < 16; ++i) {
      int idx = t + i * 256;
      int r = idx >> 6, c = idx & 63;
      wT[(size_t)(n0 + r) * DM + k0 + c] = lt[r][c];
    }
  } else if (blk == 144) {       // per-(n,k) shapley coefficients + c-float table
    if (t < NSP) {
      const int n = t;
      int cw = 0;
      for (int k = 0; k < KMC; ++k) cw += co[k * NSP + n];
      const int cwo = KMC - cw;
      const bool valid = (cw > 0) && (cwo > 0);
      float* coefT = (float*)(ws + OFF_COEF);
      float* cfS = (float*)(ws + OFF_CFS);
      for (int k = 0; k < 28; ++k) {
        float v = 0.f;
        if (valid && k < KMC) v = co[k * NSP + n] ? (1.f / (float)cw) : (-1.f / (float)cwo);
        coefT[n * 28 + k] = v;
      }
      for (int k = 0; k < 32; ++k)
        cfS[n * 32 + k] = (k < KMC) ? (float)co[k * NSP + n] : 0.f;
    }
  } else {                       // zero norm2 accumulators
    int i = (blk - 145) * 256 + t;
    if (i < MROWS) ((float*)(ws + OFF_N2))[i] = 0.f;
  }
}

// ---------------- kernel A: s[b,k,:] = sum_n c[k,n] * f[b,n,:], write bf16 ---
// Coalition row is wave-uniform -> scalar (s_load) path; cfS passed as its own
// restrict pointer so scalarization is provably safe. All register-array
// indices are compile-time static (unroll 8 + "& 7") -- no scratch.
__global__ __launch_bounds__(192) void kA(const float* __restrict__ f,
                                          const float* __restrict__ cfS,
                                          __hip_bfloat16* __restrict__ s) {
  const int b = blockIdx.x;
  const int half = blockIdx.y;     // d-half (0: d<384, 1: d>=384)
  const int t = threadIdx.x;
  const int d0 = half * 384 + t * 2;
  const float* fb = f + (size_t)b * NSP * DM + d0;

  float2 acc[KMC];
  #pragma unroll
  for (int k = 0; k < KMC; ++k) { acc[k].x = 0.f; acc[k].y = 0.f; }

  float2 vbuf[8];                  // 8-deep prefetch, statically indexed
  #pragma unroll
  for (int p = 0; p < 8; ++p) vbuf[p] = *(const float2*)(fb + (size_t)p * DM);

  #pragma unroll 8
  for (int n = 0; n < NSP - 8; ++n) {
    float2 v = vbuf[n & 7];
    vbuf[n & 7] = *(const float2*)(fb + (size_t)(n + 8) * DM);
    const float* __restrict__ cfn = cfS + n * 32;   // uniform addr -> s_load
    #pragma unroll
    for (int k = 0; k < KMC; ++k) {
      float c = cfn[k];            // SGPR; v_fmac_f32 dst, s, v
      acc[k].x = fmaf(c, v.x, acc[k].x);
      acc[k].y = fmaf(c, v.y, acc[k].y);
    }
  }
  #pragma unroll
  for (int n = NSP - 8; n < NSP; ++n) {
    float2 v = vbuf[n & 7];
    const float* __restrict__ cfn = cfS + n * 32;
    #pragma unroll
    for (int k = 0; k < KMC; ++k) {
      float c = cfn[k];
      acc[k].x = fmaf(c, v.x, acc[k].x);
      acc[k].y = fmaf(c, v.y, acc[k].y);
    }
  }

  #pragma unroll
  for (int k = 0; k < KMC; ++k) {
    union { unsigned short h[2]; u32 u; } pk;
    __hip_bfloat16 h0 = __float2bfloat16(acc[k].x);
    __hip_bfloat16 h1 = __float2bfloat16(acc[k].y);
    pk.h[0] = *(unsigned short*)&h0;
    pk.h[1] = *(unsigned short*)&h1;
    *(u32*)((char*)(s + (size_t)(b * KMC + k) * DM + d0)) = pk.u;
  }
}

// ---------------- kernel B: norm2[row] += rowwise |s @ wT^T|^2 (bf16 MFMA) ---
#define BM 128
#define BN 192
#define BK 32
#define NTK 24   // 768/32

__global__ __launch_bounds__(256) void kB(char* __restrict__ ws) {
  const int bid = blockIdx.x;      // grid 200 = 50 (M) * 4 (N)
  const int tm = bid >> 2;
  const int tn = bid & 3;
  const int tid = threadIdx.x;
  const int wid = tid >> 6;
  const int lane = tid & 63;
  const int wm = wid >> 1;         // 2x2 wave grid: 64 rows x 96 cols per wave
  const int wn = wid & 1;

  const __hip_bfloat16* S  = (const __hip_bfloat16*)(ws + OFF_S);
  const __hip_bfloat16* WT = (const __hip_bfloat16*)(ws + OFF_WT);
  float* norm2 = (float*)(ws + OFF_N2);

  __shared__ __align__(16) char As[2][BM * BK * 2];  // [128][32] bf16, 64B rows
  __shared__ __align__(16) char Bs[2][BN * BK * 2];  // [192][32] bf16, 64B rows

  // staging: global src pre-swizzled (slot ^= (r>>1)&3), LDS dest linear
  const char* gA[2]; char *lA0[2], *lA1[2];
  #pragma unroll
  for (int j = 0; j < 2; ++j) {
    int li = (wid * 2 + j) * 64 + lane;
    int r = li >> 2, sl = li & 3;
    int slx = sl ^ ((r >> 1) & 3);
    gA[j] = (const char*)(S + (size_t)(tm * BM + r) * DM) + slx * 16;
    lA0[j] = As[0] + (wid * 2 + j) * 1024;
    lA1[j] = As[1] + (wid * 2 + j) * 1024;
  }
  const char* gB[3]; char *lB0[3], *lB1[3];
  #pragma unroll
  for (int j = 0; j < 3; ++j) {
    int li = (wid * 3 + j) * 64 + lane;
    int r = li >> 2, sl = li & 3;
    int slx = sl ^ ((r >> 1) & 3);
    gB[j] = (const char*)(WT + (size_t)(tn * BN + r) * DM) + slx * 16;
    lB0[j] = Bs[0] + (wid * 3 + j) * 1024;
    lB1[j] = Bs[1] + (wid * 3 + j) * 1024;
  }

  auto stage = [&](int tk, int bsel) {
    size_t koff = (size_t)tk * (BK * 2);   // 64 bytes per K-step
    #pragma unroll
    for (int j = 0; j < 2; ++j) GLOAD_LDS16(gA[j] + koff, bsel ? lA1[j] : lA0[j]);
    #pragma unroll
    for (int j = 0; j < 3; ++j) GLOAD_LDS16(gB[j] + koff, bsel ? lB1[j] : lB0[j]);
  };

  f32x4 acc[4][6];
  #pragma unroll
  for (int m = 0; m < 4; ++m)
    #pragma unroll
    for (int n = 0; n < 6; ++n)
      #pragma unroll
      for (int j = 0; j < 4; ++j) acc[m][n][j] = 0.f;

  // fragment read offsets (swizzled to match stage-source permutation)
  int offA[4], offB[6];
  #pragma unroll
  for (int m = 0; m < 4; ++m) {
    int r = wm * 64 + m * 16 + (lane & 15);
    int sl = (lane >> 4) ^ ((r >> 1) & 3);
    offA[m] = r * 64 + sl * 16;
  }
  #pragma unroll
  for (int n = 0; n < 6; ++n) {
    int r = wn * 96 + n * 16 + (lane & 15);
    int sl = (lane >> 4) ^ ((r >> 1) & 3);
    offB[n] = r * 64 + sl * 16;
  }

  stage(0, 0);
  for (int tk = 0; tk < NTK; ++tk) {
    int cur = tk & 1;
    __syncthreads();               // drains vmcnt(0): staged tile ready
    if (tk + 1 < NTK) stage(tk + 1, cur ^ 1);
    bf16x8 af[4], bfr[6];
    #pragma unroll
    for (int m = 0; m < 4; ++m) af[m] = *(const bf16x8*)(As[cur] + offA[m]);
    #pragma unroll
    for (int n = 0; n < 6; ++n) bfr[n] = *(const bf16x8*)(Bs[cur] + offB[n]);
    #pragma unroll
    for (int m = 0; m < 4; ++m)
      #pragma unroll
      for (int n = 0; n < 6; ++n)
        acc[m][n] = __builtin_amdgcn_mfma_f32_16x16x32_bf16(af[m], bfr[n], acc[m][n], 0, 0, 0);
  }

  // epilogue: sum of squares over this block's 96-col slice, reduce 16 lanes,
  // atomicAdd into norm2[row]  (C/D layout: col=lane&15, row=(lane>>4)*4+reg)
  float ps[4][4];
  #pragma unroll
  for (int m = 0; m < 4; ++m)
    #pragma unroll
    for (int i = 0; i < 4; ++i) {
      float v = 0.f;
      #pragma unroll
      for (int n = 0; n < 6; ++n) { float x = acc[m][n][i]; v += x * x; }
      #pragma unroll
      for (int d = 1; d < 16; d <<= 1) v += __shfl_xor(v, d, 64);
      ps[m][i] = v;
    }
  if ((lane & 15) == 0) {
    int g = lane >> 4;
    #pragma unroll
    for (int m = 0; m < 4; ++m)
      #pragma unroll
      for (int i = 0; i < 4; ++i)
        atomicAdd(&norm2[tm * BM + wm * 64 + m * 16 + g * 4 + i], ps[m][i]);
  }
}

// ---------------- kernel C: cv = relu(sqrt(norm2)*scale); shapley ------------
__global__ __launch_bounds__(128) void kC(const char* __restrict__ ws,
                                          const float* __restrict__ scale,
                                          float* __restrict__ out) {
  const int b = blockIdx.x, n = threadIdx.x;
  const float* norm2 = (const float*)(ws + OFF_N2);
  const float* coefT = (const float*)(ws + OFF_COEF);
  __shared__ float cvs[32];
  if (n < KMC) {
    float nv = norm2[b * KMC + n];
    cvs[n] = fmaxf(sqrtf(fmaxf(nv, 0.f)) * scale[0], 0.f);
  } else if (n < 32) {
    cvs[n] = 0.f;
  }
  __syncthreads();
  float sum = 0.f;
  #pragma unroll
  for (int k = 0; k < KMC; ++k) sum += cvs[k] * coefT[n * 28 + k];
  out[b * NSP + n] = sum;
}

extern "C" void kernel_launch(void* const* d_in, const int* in_sizes, int n_in,
                              void* d_out, int out_size, void* d_ws, size_t ws_size,
                              hipStream_t stream) {
  const float* features   = (const float*)d_in[0];
  const int*   coalitions = (const int*)d_in[1];
  const float* wv         = (const float*)d_in[2];
  const float* scale      = (const float*)d_in[3];
  char* ws = (char*)d_ws;

  prep_kernel<<<171, 256, 0, stream>>>(wv, coalitions, ws);
  dim3 ga(NB, 2);
  kA<<<ga, 192, 0, stream>>>(features, (const float*)(ws + OFF_CFS),
                             (__hip_bfloat16*)(ws + OFF_S));
  kB<<<200, 256, 0, stream>>>(ws);
  kC<<<NB, 128, 0, stream>>>(ws, scale, (float*)d_out);
}

// Round 4
// 52.521 us; speedup vs baseline: 1.7495x; 1.2206x over previous
//
#include <hip/hip_runtime.h>
#include <hip/hip_bf16.h>
#include <stdint.h>

#define NB  256     // batch
#define NSP 128     // n_spins
#define DM  768     // d_model
#define KMC 25      // coalitions
#define MROWS (NB*KMC)  // 6400

// workspace layout (bytes), all 256-aligned (ws is 384 MiB)
#define OFF_S    0u          // s bf16 [6400][768]          9,830,400 B
#define OFF_WT   9830400u    // w_v^T bf16 [768][768]       1,179,648 B
#define OFF_N2   11010048u   // norm2 f32 [6400]               25,600 B
#define OFF_COEF 11035648u   // coefT f32 [128][28]            14,336 B
#define OFF_CB   11049984u   // Cb bf16 [32][128] (pad rows)    8,192 B

typedef __attribute__((ext_vector_type(8))) short bf16x8;
typedef __attribute__((ext_vector_type(4))) float f32x4;
typedef unsigned int u32;

#define GLOAD_LDS16(gp, lp) \
  __builtin_amdgcn_global_load_lds((const __attribute__((address_space(1))) u32*)(gp), \
                                   (__attribute__((address_space(3))) u32*)(lp), 16, 0, 0)

// ---------------- prep: transpose w_v -> bf16 wT, coef/C tables, zero norm2 -
__global__ __launch_bounds__(256) void prep_kernel(const float* __restrict__ wv,
                                                   const int* __restrict__ co,
                                                   char* __restrict__ ws) {
  const int blk = blockIdx.x;
  const int t = threadIdx.x;
  if (blk < 144) {               // 12x12 tiles of 64x64: wT[n][k] = bf16(wv[k][n])
    __shared__ __hip_bfloat16 lt[64][66];
    const int bi = blk / 12, bj = blk % 12;
    const int k0 = bi * 64, n0 = bj * 64;
    #pragma unroll
    for (int i = 0; i < 16; ++i) {
      int idx = t + i * 256;
      int r = idx >> 6, c = idx & 63;
      lt[c][r] = __float2bfloat16(wv[(size_t)(k0 + r) * DM + n0 + c]);
    }
    __syncthreads();
    __hip_bfloat16* wT = (__hip_bfloat16*)(ws + OFF_WT);
    #pragma unroll
    for (int i = 0; i < 16; ++i) {
      int idx = t + i * 256;
      int r = idx >> 6, c = idx & 63;
      wT[(size_t)(n0 + r) * DM + k0 + c] = lt[r][c];
    }
  } else if (blk == 144) {       // per-(n,k) shapley coefficients
    if (t < NSP) {
      const int n = t;
      int cw = 0;
      for (int k = 0; k < KMC; ++k) cw += co[k * NSP + n];
      const int cwo = KMC - cw;
      const bool valid = (cw > 0) && (cwo > 0);
      float* coefT = (float*)(ws + OFF_COEF);
      for (int k = 0; k < 28; ++k) {
        float v = 0.f;
        if (valid && k < KMC) v = co[k * NSP + n] ? (1.f / (float)cw) : (-1.f / (float)cwo);
        coefT[n * 28 + k] = v;
      }
    }
  } else if (blk < 170) {        // zero norm2 accumulators
    int i = (blk - 145) * 256 + t;
    if (i < MROWS) ((float*)(ws + OFF_N2))[i] = 0.f;
  } else {                       // Cb bf16 [32][128], rows >= KMC zero-padded
    __hip_bfloat16* Cb = (__hip_bfloat16*)(ws + OFF_CB);
    for (int i = t; i < 32 * NSP; i += 256) {
      int k = i >> 7, n = i & 127;
      float v = (k < KMC) ? (float)co[k * NSP + n] : 0.f;
      Cb[i] = __float2bfloat16(v);
    }
  }
}

// ---------------- kernel A: s[b] = C(25x128) x F_b(128x768) via bf16 MFMA ---
// C loaded once into 8 static A-fragments; F streamed through registers with
// in-register f32->bf16 convert. Double-buffered d-tiles, fully unrolled
// (all register-array indices compile-time -> no scratch). No LDS, no s_loads.
__global__ __launch_bounds__(256) void kA(const float* __restrict__ f,
                                          const __hip_bfloat16* __restrict__ Cb,
                                          __hip_bfloat16* __restrict__ s) {
  const int b = blockIdx.x;
  const int half = blockIdx.y;      // d-half: [half*384, half*384+384)
  const int tid = threadIdx.x;
  const int w = tid >> 6;           // 4 waves, 96 d-cols each
  const int lane = tid & 63;
  const int lo = lane & 15, hi = lane >> 4;

  // A-fragments (coalition rows): A0 rows 0-15, A1 rows 16-31 (16x16x32 layout:
  // row = lane&15, k = (lane>>4)*8 + j)
  bf16x8 A0[4], A1[4];
  #pragma unroll
  for (int ks = 0; ks < 4; ++ks) {
    A0[ks] = *(const bf16x8*)(Cb + (size_t)lo * NSP + ks * 32 + hi * 8);
    A1[ks] = *(const bf16x8*)(Cb + (size_t)(16 + lo) * NSP + ks * 32 + hi * 8);
  }

  const int dbase = half * 384 + w * 96;
  const float* fb = f + (size_t)b * NSP * DM + dbase + lo;

#define LOADT(dt, buf) { \
    const float* p_ = fb + (dt) * 16; \
    _Pragma("unroll") for (int ks = 0; ks < 4; ++ks) \
      _Pragma("unroll") for (int j = 0; j < 8; ++j) \
        buf[ks * 8 + j] = p_[(size_t)(ks * 32 + hi * 8 + j) * DM]; }

#define COMPUTE(dt, buf) { \
    bf16x8 Bf[4]; \
    _Pragma("unroll") for (int ks = 0; ks < 4; ++ks) \
      _Pragma("unroll") for (int j = 0; j < 8; ++j) { \
        __hip_bfloat16 h_ = __float2bfloat16(buf[ks * 8 + j]); \
        Bf[ks][j] = *(short*)&h_; } \
    f32x4 ac0 = {0.f, 0.f, 0.f, 0.f}, ac1 = {0.f, 0.f, 0.f, 0.f}; \
    _Pragma("unroll") for (int ks = 0; ks < 4; ++ks) { \
      ac0 = __builtin_amdgcn_mfma_f32_16x16x32_bf16(A0[ks], Bf[ks], ac0, 0, 0, 0); \
      ac1 = __builtin_amdgcn_mfma_f32_16x16x32_bf16(A1[ks], Bf[ks], ac1, 0, 0, 0); } \
    _Pragma("unroll") for (int i = 0; i < 4; ++i) { \
      int r0_ = hi * 4 + i; \
      s[((size_t)(b * KMC) + r0_) * DM + dbase + (dt) * 16 + lo] = __float2bfloat16(ac0[i]); \
      int r1_ = 16 + hi * 4 + i; \
      if (r1_ < KMC) \
        s[((size_t)(b * KMC) + r1_) * DM + dbase + (dt) * 16 + lo] = __float2bfloat16(ac1[i]); } }

  float bufA[32], bufB[32];
  LOADT(0, bufA)
  #pragma unroll
  for (int dt = 0; dt < 6; dt += 2) {
    if (dt + 1 < 6) LOADT(dt + 1, bufB)
    COMPUTE(dt, bufA)
    if (dt + 2 < 6) LOADT(dt + 2, bufA)
    if (dt + 1 < 6) COMPUTE(dt + 1, bufB)
  }
#undef LOADT
#undef COMPUTE
}

// ---------------- kernel B: norm2[row] += rowwise |s @ wT^T|^2 (bf16 MFMA) ---
#define BM 128
#define BN 192
#define BK 32
#define NTK 24   // 768/32

__global__ __launch_bounds__(256) void kB(char* __restrict__ ws) {
  const int bid = blockIdx.x;      // grid 200 = 50 (M) * 4 (N)
  const int tm = bid >> 2;
  const int tn = bid & 3;
  const int tid = threadIdx.x;
  const int wid = tid >> 6;
  const int lane = tid & 63;
  const int wm = wid >> 1;         // 2x2 wave grid: 64 rows x 96 cols per wave
  const int wn = wid & 1;

  const __hip_bfloat16* S  = (const __hip_bfloat16*)(ws + OFF_S);
  const __hip_bfloat16* WT = (const __hip_bfloat16*)(ws + OFF_WT);
  float* norm2 = (float*)(ws + OFF_N2);

  __shared__ __align__(16) char As[2][BM * BK * 2];  // [128][32] bf16, 64B rows
  __shared__ __align__(16) char Bs[2][BN * BK * 2];  // [192][32] bf16, 64B rows

  // staging: global src pre-swizzled (slot ^= (r>>1)&3), LDS dest linear
  const char* gA[2]; char *lA0[2], *lA1[2];
  #pragma unroll
  for (int j = 0; j < 2; ++j) {
    int li = (wid * 2 + j) * 64 + lane;
    int r = li >> 2, sl = li & 3;
    int slx = sl ^ ((r >> 1) & 3);
    gA[j] = (const char*)(S + (size_t)(tm * BM + r) * DM) + slx * 16;
    lA0[j] = As[0] + (wid * 2 + j) * 1024;
    lA1[j] = As[1] + (wid * 2 + j) * 1024;
  }
  const char* gB[3]; char *lB0[3], *lB1[3];
  #pragma unroll
  for (int j = 0; j < 3; ++j) {
    int li = (wid * 3 + j) * 64 + lane;
    int r = li >> 2, sl = li & 3;
    int slx = sl ^ ((r >> 1) & 3);
    gB[j] = (const char*)(WT + (size_t)(tn * BN + r) * DM) + slx * 16;
    lB0[j] = Bs[0] + (wid * 3 + j) * 1024;
    lB1[j] = Bs[1] + (wid * 3 + j) * 1024;
  }

  auto stage = [&](int tk, int bsel) {
    size_t koff = (size_t)tk * (BK * 2);   // 64 bytes per K-step
    #pragma unroll
    for (int j = 0; j < 2; ++j) GLOAD_LDS16(gA[j] + koff, bsel ? lA1[j] : lA0[j]);
    #pragma unroll
    for (int j = 0; j < 3; ++j) GLOAD_LDS16(gB[j] + koff, bsel ? lB1[j] : lB0[j]);
  };

  f32x4 acc[4][6];
  #pragma unroll
  for (int m = 0; m < 4; ++m)
    #pragma unroll
    for (int n = 0; n < 6; ++n)
      #pragma unroll
      for (int j = 0; j < 4; ++j) acc[m][n][j] = 0.f;

  // fragment read offsets (swizzled to match stage-source permutation)
  int offA[4], offB[6];
  #pragma unroll
  for (int m = 0; m < 4; ++m) {
    int r = wm * 64 + m * 16 + (lane & 15);
    int sl = (lane >> 4) ^ ((r >> 1) & 3);
    offA[m] = r * 64 + sl * 16;
  }
  #pragma unroll
  for (int n = 0; n < 6; ++n) {
    int r = wn * 96 + n * 16 + (lane & 15);
    int sl = (lane >> 4) ^ ((r >> 1) & 3);
    offB[n] = r * 64 + sl * 16;
  }

  stage(0, 0);
  for (int tk = 0; tk < NTK; ++tk) {
    int cur = tk & 1;
    __syncthreads();               // drains vmcnt(0): staged tile ready
    if (tk + 1 < NTK) stage(tk + 1, cur ^ 1);
    bf16x8 af[4], bfr[6];
    #pragma unroll
    for (int m = 0; m < 4; ++m) af[m] = *(const bf16x8*)(As[cur] + offA[m]);
    #pragma unroll
    for (int n = 0; n < 6; ++n) bfr[n] = *(const bf16x8*)(Bs[cur] + offB[n]);
    #pragma unroll
    for (int m = 0; m < 4; ++m)
      #pragma unroll
      for (int n = 0; n < 6; ++n)
        acc[m][n] = __builtin_amdgcn_mfma_f32_16x16x32_bf16(af[m], bfr[n], acc[m][n], 0, 0, 0);
  }

  // epilogue: sum of squares over this block's 96-col slice, reduce 16 lanes,
  // atomicAdd into norm2[row]  (C/D layout: col=lane&15, row=(lane>>4)*4+reg)
  float ps[4][4];
  #pragma unroll
  for (int m = 0; m < 4; ++m)
    #pragma unroll
    for (int i = 0; i < 4; ++i) {
      float v = 0.f;
      #pragma unroll
      for (int n = 0; n < 6; ++n) { float x = acc[m][n][i]; v += x * x; }
      #pragma unroll
      for (int d = 1; d < 16; d <<= 1) v += __shfl_xor(v, d, 64);
      ps[m][i] = v;
    }
  if ((lane & 15) == 0) {
    int g = lane >> 4;
    #pragma unroll
    for (int m = 0; m < 4; ++m)
      #pragma unroll
      for (int i = 0; i < 4; ++i)
        atomicAdd(&norm2[tm * BM + wm * 64 + m * 16 + g * 4 + i], ps[m][i]);
  }
}

// ---------------- kernel C: cv = relu(sqrt(norm2)*scale); shapley ------------
__global__ __launch_bounds__(128) void kC(const char* __restrict__ ws,
                                          const float* __restrict__ scale,
                                          float* __restrict__ out) {
  const int b = blockIdx.x, n = threadIdx.x;
  const float* norm2 = (const float*)(ws + OFF_N2);
  const float* coefT = (const float*)(ws + OFF_COEF);
  __shared__ float cvs[32];
  if (n < KMC) {
    float nv = norm2[b * KMC + n];
    cvs[n] = fmaxf(sqrtf(fmaxf(nv, 0.f)) * scale[0], 0.f);
  } else if (n < 32) {
    cvs[n] = 0.f;
  }
  __syncthreads();
  float sum = 0.f;
  #pragma unroll
  for (int k = 0; k < KMC; ++k) sum += cvs[k] * coefT[n * 28 + k];
  out[b * NSP + n] = sum;
}

extern "C" void kernel_launch(void* const* d_in, const int* in_sizes, int n_in,
                              void* d_out, int out_size, void* d_ws, size_t ws_size,
                              hipStream_t stream) {
  const float* features   = (const float*)d_in[0];
  const int*   coalitions = (const int*)d_in[1];
  const float* wv         = (const float*)d_in[2];
  const float* scale      = (const float*)d_in[3];
  char* ws = (char*)d_ws;

  prep_kernel<<<171, 256, 0, stream>>>(wv, coalitions, ws);
  dim3 ga(NB, 2);
  kA<<<ga, 256, 0, stream>>>(features, (const __hip_bfloat16*)(ws + OFF_CB),
                             (__hip_bfloat16*)(ws + OFF_S));
  kB<<<200, 256, 0, stream>>>(ws);
  kC<<<NB, 128, 0, stream>>>(ws, scale, (float*)d_out);
}

// Round 5
// 50.916 us; speedup vs baseline: 1.8046x; 1.0315x over previous
//
#include <hip/hip_runtime.h>
#include <hip/hip_bf16.h>
#include <stdint.h>

#define NB  256     // batch
#define NSP 128     // n_spins
#define DM  768     // d_model
#define KMC 25      // coalitions
#define MROWS (NB*KMC)  // 6400

// workspace layout (bytes), all 256-aligned (ws is 384 MiB)
#define OFF_S    0u          // s bf16 [6400][768]          9,830,400 B
#define OFF_WT   9830400u    // w_v^T bf16 [768][768]       1,179,648 B
#define OFF_N2   11010048u   // norm2 f32 [6400]               25,600 B
#define OFF_COEF 11035648u   // coefT f32 [128][28]            14,336 B
#define OFF_CB   11049984u   // Cb bf16 [32][128] (pad rows)    8,192 B

typedef __attribute__((ext_vector_type(8))) short bf16x8;
typedef __attribute__((ext_vector_type(4))) float f32x4;
typedef unsigned int u32;

#define GLOAD_LDS16(gp, lp) \
  __builtin_amdgcn_global_load_lds((const __attribute__((address_space(1))) u32*)(gp), \
                                   (__attribute__((address_space(3))) u32*)(lp), 16, 0, 0)

// ---------------- prep: transpose w_v -> bf16 wT, coef/C tables, zero norm2 -
__global__ __launch_bounds__(256) void prep_kernel(const float* __restrict__ wv,
                                                   const int* __restrict__ co,
                                                   char* __restrict__ ws) {
  const int blk = blockIdx.x;
  const int t = threadIdx.x;
  if (blk < 144) {               // 12x12 tiles of 64x64: wT[n][k] = bf16(wv[k][n])
    __shared__ __hip_bfloat16 lt[64][66];
    const int bi = blk / 12, bj = blk % 12;
    const int k0 = bi * 64, n0 = bj * 64;
    #pragma unroll
    for (int i = 0; i < 16; ++i) {
      int idx = t + i * 256;
      int r = idx >> 6, c = idx & 63;
      lt[c][r] = __float2bfloat16(wv[(size_t)(k0 + r) * DM + n0 + c]);
    }
    __syncthreads();
    __hip_bfloat16* wT = (__hip_bfloat16*)(ws + OFF_WT);
    #pragma unroll
    for (int i = 0; i < 16; ++i) {
      int idx = t + i * 256;
      int r = idx >> 6, c = idx & 63;
      wT[(size_t)(n0 + r) * DM + k0 + c] = lt[r][c];
    }
  } else if (blk == 144) {       // per-(n,k) shapley coefficients
    if (t < NSP) {
      const int n = t;
      int cw = 0;
      #pragma unroll
      for (int k = 0; k < KMC; ++k) cw += co[k * NSP + n];
      const int cwo = KMC - cw;
      const bool valid = (cw > 0) && (cwo > 0);
      float* coefT = (float*)(ws + OFF_COEF);
      #pragma unroll
      for (int k = 0; k < 28; ++k) {
        float v = 0.f;
        if (valid && k < KMC) v = co[k * NSP + n] ? (1.f / (float)cw) : (-1.f / (float)cwo);
        coefT[n * 28 + k] = v;
      }
    }
  } else if (blk < 170) {        // zero norm2 accumulators
    int i = (blk - 145) * 256 + t;
    if (i < MROWS) ((float*)(ws + OFF_N2))[i] = 0.f;
  } else {                       // blk 170..201: Cb row k (bf16, rows>=KMC zero)
    int k = blk - 170;
    if (t < NSP) {
      float v = (k < KMC) ? (float)co[k * NSP + t] : 0.f;
      ((__hip_bfloat16*)(ws + OFF_CB))[k * NSP + t] = __float2bfloat16(v);
    }
  }
}

// ---------------- kernel A: s[b] = C(25x128) x F_b(128x768) via bf16 MFMA ---
// F staged through LDS with global_load_lds dwordx4 (coalesced wide reads);
// column fragments read from LDS (ds_read_b32, 4-way conflict acceptable),
// converted f32->bf16 in-register. C held in 8 static A-fragments.
// 48 KB LDS -> 3 blocks/CU = 12 waves/CU.
__global__ __launch_bounds__(256, 3) void kA(const float* __restrict__ f,
                                             const __hip_bfloat16* __restrict__ Cb,
                                             __hip_bfloat16* __restrict__ s) {
  const int b = blockIdx.x;
  const int dslice = blockIdx.y;   // 4 slices x 192 cols
  const int tid = threadIdx.x;
  const int w = tid >> 6;          // 4 waves, 48 cols each
  const int lane = tid & 63;
  const int lo = lane & 15, hi = lane >> 4;

  __shared__ __align__(16) float Fs[2][32 * 192];   // 24 KB per buffer

  // A-fragments (coalition rows), k = ks*32 + hi*8 + j
  bf16x8 A0[4], A1[4];
  #pragma unroll
  for (int ks = 0; ks < 4; ++ks) {
    A0[ks] = *(const bf16x8*)(Cb + (size_t)lo * NSP + ks * 32 + hi * 8);
    A1[ks] = *(const bf16x8*)(Cb + (size_t)(16 + lo) * NSP + ks * 32 + hi * 8);
  }

  // staging sources: wave w fills windows 6w..6w+5 (1024 B each) = rows 8w..8w+7
  const float* fbase = f + (size_t)b * NSP * DM + dslice * 192;
  const float* gsrc[6];
  #pragma unroll
  for (int q = 0; q < 6; ++q) {
    int e = (w * 6 + q) * 256 + lane * 4;   // float index into [32][192] chunk
    int r = e / 192, c = e % 192;           // 4|192 -> lane's 16B stays in-row
    gsrc[q] = fbase + (size_t)r * DM + c;
  }

  f32x4 ac0[3], ac1[3];
  #pragma unroll
  for (int ct = 0; ct < 3; ++ct)
    #pragma unroll
    for (int i = 0; i < 4; ++i) { ac0[ct][i] = 0.f; ac1[ct][i] = 0.f; }

  // prologue stage of K-chunk 0
  #pragma unroll
  for (int q = 0; q < 6; ++q)
    GLOAD_LDS16(gsrc[q], &Fs[0][(w * 6 + q) * 256]);

  #pragma unroll
  for (int ks = 0; ks < 4; ++ks) {
    const int bb = ks & 1;
    __syncthreads();               // drains vmcnt(0): buffer bb staged
    if (ks < 3) {
      #pragma unroll
      for (int q = 0; q < 6; ++q)
        GLOAD_LDS16(gsrc[q] + (size_t)(ks + 1) * 32 * DM, &Fs[bb ^ 1][(w * 6 + q) * 256]);
    }
    #pragma unroll
    for (int ct = 0; ct < 3; ++ct) {
      bf16x8 Bf;
      #pragma unroll
      for (int j = 0; j < 8; ++j) {
        float v = Fs[bb][(hi * 8 + j) * 192 + w * 48 + ct * 16 + lo];
        __hip_bfloat16 h = __float2bfloat16(v);
        Bf[j] = *(short*)&h;
      }
      ac0[ct] = __builtin_amdgcn_mfma_f32_16x16x32_bf16(A0[ks], Bf, ac0[ct], 0, 0, 0);
      ac1[ct] = __builtin_amdgcn_mfma_f32_16x16x32_bf16(A1[ks], Bf, ac1[ct], 0, 0, 0);
    }
  }

  // epilogue: D layout col=lane&15, row=(lane>>4)*4+i
  #pragma unroll
  for (int ct = 0; ct < 3; ++ct) {
    int dcol = dslice * 192 + w * 48 + ct * 16 + lo;
    #pragma unroll
    for (int i = 0; i < 4; ++i) {
      int r0 = hi * 4 + i;
      s[((size_t)b * KMC + r0) * DM + dcol] = __float2bfloat16(ac0[ct][i]);
      int r1 = 16 + hi * 4 + i;
      if (r1 < KMC)
        s[((size_t)b * KMC + r1) * DM + dcol] = __float2bfloat16(ac1[ct][i]);
    }
  }
}

// ---------------- kernel B: norm2[row] += rowwise |s @ wT^T|^2 (bf16 MFMA) ---
#define BM 128
#define BN 192
#define BK 32
#define NTK 24   // 768/32

__global__ __launch_bounds__(256) void kB(char* __restrict__ ws) {
  const int bid = blockIdx.x;      // grid 200 = 50 (M) * 4 (N)
  const int tm = bid >> 2;
  const int tn = bid & 3;
  const int tid = threadIdx.x;
  const int wid = tid >> 6;
  const int lane = tid & 63;
  const int wm = wid >> 1;         // 2x2 wave grid: 64 rows x 96 cols per wave
  const int wn = wid & 1;

  const __hip_bfloat16* S  = (const __hip_bfloat16*)(ws + OFF_S);
  const __hip_bfloat16* WT = (const __hip_bfloat16*)(ws + OFF_WT);
  float* norm2 = (float*)(ws + OFF_N2);

  __shared__ __align__(16) char As[2][BM * BK * 2];  // [128][32] bf16, 64B rows
  __shared__ __align__(16) char Bs[2][BN * BK * 2];  // [192][32] bf16, 64B rows

  // staging: global src pre-swizzled (slot ^= (r>>1)&3), LDS dest linear
  const char* gA[2]; char *lA0[2], *lA1[2];
  #pragma unroll
  for (int j = 0; j < 2; ++j) {
    int li = (wid * 2 + j) * 64 + lane;
    int r = li >> 2, sl = li & 3;
    int slx = sl ^ ((r >> 1) & 3);
    gA[j] = (const char*)(S + (size_t)(tm * BM + r) * DM) + slx * 16;
    lA0[j] = As[0] + (wid * 2 + j) * 1024;
    lA1[j] = As[1] + (wid * 2 + j) * 1024;
  }
  const char* gB[3]; char *lB0[3], *lB1[3];
  #pragma unroll
  for (int j = 0; j < 3; ++j) {
    int li = (wid * 3 + j) * 64 + lane;
    int r = li >> 2, sl = li & 3;
    int slx = sl ^ ((r >> 1) & 3);
    gB[j] = (const char*)(WT + (size_t)(tn * BN + r) * DM) + slx * 16;
    lB0[j] = Bs[0] + (wid * 3 + j) * 1024;
    lB1[j] = Bs[1] + (wid * 3 + j) * 1024;
  }

  auto stage = [&](int tk, int bsel) {
    size_t koff = (size_t)tk * (BK * 2);   // 64 bytes per K-step
    #pragma unroll
    for (int j = 0; j < 2; ++j) GLOAD_LDS16(gA[j] + koff, bsel ? lA1[j] : lA0[j]);
    #pragma unroll
    for (int j = 0; j < 3; ++j) GLOAD_LDS16(gB[j] + koff, bsel ? lB1[j] : lB0[j]);
  };

  f32x4 acc[4][6];
  #pragma unroll
  for (int m = 0; m < 4; ++m)
    #pragma unroll
    for (int n = 0; n < 6; ++n)
      #pragma unroll
      for (int j = 0; j < 4; ++j) acc[m][n][j] = 0.f;

  // fragment read offsets (swizzled to match stage-source permutation)
  int offA[4], offB[6];
  #pragma unroll
  for (int m = 0; m < 4; ++m) {
    int r = wm * 64 + m * 16 + (lane & 15);
    int sl = (lane >> 4) ^ ((r >> 1) & 3);
    offA[m] = r * 64 + sl * 16;
  }
  #pragma unroll
  for (int n = 0; n < 6; ++n) {
    int r = wn * 96 + n * 16 + (lane & 15);
    int sl = (lane >> 4) ^ ((r >> 1) & 3);
    offB[n] = r * 64 + sl * 16;
  }

  stage(0, 0);
  for (int tk = 0; tk < NTK; ++tk) {
    int cur = tk & 1;
    __syncthreads();               // drains vmcnt(0): staged tile ready
    if (tk + 1 < NTK) stage(tk + 1, cur ^ 1);
    bf16x8 af[4], bfr[6];
    #pragma unroll
    for (int m = 0; m < 4; ++m) af[m] = *(const bf16x8*)(As[cur] + offA[m]);
    #pragma unroll
    for (int n = 0; n < 6; ++n) bfr[n] = *(const bf16x8*)(Bs[cur] + offB[n]);
    #pragma unroll
    for (int m = 0; m < 4; ++m)
      #pragma unroll
      for (int n = 0; n < 6; ++n)
        acc[m][n] = __builtin_amdgcn_mfma_f32_16x16x32_bf16(af[m], bfr[n], acc[m][n], 0, 0, 0);
  }

  // epilogue: sum of squares over this block's 96-col slice, reduce 16 lanes,
  // atomicAdd into norm2[row]  (C/D layout: col=lane&15, row=(lane>>4)*4+reg)
  float ps[4][4];
  #pragma unroll
  for (int m = 0; m < 4; ++m)
    #pragma unroll
    for (int i = 0; i < 4; ++i) {
      float v = 0.f;
      #pragma unroll
      for (int n = 0; n < 6; ++n) { float x = acc[m][n][i]; v += x * x; }
      #pragma unroll
      for (int d = 1; d < 16; d <<= 1) v += __shfl_xor(v, d, 64);
      ps[m][i] = v;
    }
  if ((lane & 15) == 0) {
    int g = lane >> 4;
    #pragma unroll
    for (int m = 0; m < 4; ++m)
      #pragma unroll
      for (int i = 0; i < 4; ++i)
        atomicAdd(&norm2[tm * BM + wm * 64 + m * 16 + g * 4 + i], ps[m][i]);
  }
}

// ---------------- kernel C: cv = relu(sqrt(norm2)*scale); shapley ------------
__global__ __launch_bounds__(128) void kC(const char* __restrict__ ws,
                                          const float* __restrict__ scale,
                                          float* __restrict__ out) {
  const int b = blockIdx.x, n = threadIdx.x;
  const float* norm2 = (const float*)(ws + OFF_N2);
  const float* coefT = (const float*)(ws + OFF_COEF);
  __shared__ float cvs[32];
  if (n < KMC) {
    float nv = norm2[b * KMC + n];
    cvs[n] = fmaxf(sqrtf(fmaxf(nv, 0.f)) * scale[0], 0.f);
  } else if (n < 32) {
    cvs[n] = 0.f;
  }
  __syncthreads();
  float sum = 0.f;
  #pragma unroll
  for (int k = 0; k < KMC; ++k) sum += cvs[k] * coefT[n * 28 + k];
  out[b * NSP + n] = sum;
}

extern "C" void kernel_launch(void* const* d_in, const int* in_sizes, int n_in,
                              void* d_out, int out_size, void* d_ws, size_t ws_size,
                              hipStream_t stream) {
  const float* features   = (const float*)d_in[0];
  const int*   coalitions = (const int*)d_in[1];
  const float* wv         = (const float*)d_in[2];
  const float* scale      = (const float*)d_in[3];
  char* ws = (char*)d_ws;

  prep_kernel<<<202, 256, 0, stream>>>(wv, coalitions, ws);
  dim3 ga(NB, 4);
  kA<<<ga, 256, 0, stream>>>(features, (const __hip_bfloat16*)(ws + OFF_CB),
                             (__hip_bfloat16*)(ws + OFF_S));
  kB<<<200, 256, 0, stream>>>(ws);
  kC<<<NB, 128, 0, stream>>>(ws, scale, (float*)d_out);
}